// Round 7
// baseline (332.195 us; speedup 1.0000x reference)
//
#include <hip/hip_runtime.h>

typedef unsigned short u16;
typedef __bf16 bf16x8_t __attribute__((ext_vector_type(8)));
typedef float  f32x4_t  __attribute__((ext_vector_type(4)));
typedef u16    us8_t    __attribute__((ext_vector_type(8)));
typedef u16    us4_t    __attribute__((ext_vector_type(4)));

__device__ __forceinline__ u16 f2bf(float f) {
    __bf16 h = (__bf16)f;
    return __builtin_bit_cast(u16, h);
}
__device__ __forceinline__ bf16x8_t ld_bf8(const u16* p) {
    us8_t u = *(const us8_t*)p;
    return __builtin_bit_cast(bf16x8_t, u);
}
__device__ __forceinline__ f32x4_t mfma16(bf16x8_t a, bf16x8_t b, f32x4_t c) {
    return __builtin_amdgcn_mfma_f32_16x16x32_bf16(a, b, c, 0, 0, 0);
}
__device__ __forceinline__ float exp2_fast(float x) {
#if __has_builtin(__builtin_amdgcn_exp2f)
    return __builtin_amdgcn_exp2f(x);
#else
    return exp2f(x);
#endif
}

// async global->LDS, 16B per lane. LDS dest MUST be base + lane*16 (wave-uniform base).
__device__ __forceinline__ void dma16(const u16* g, u16* l) {
#if __has_builtin(__builtin_amdgcn_global_load_lds)
    __builtin_amdgcn_global_load_lds((const __attribute__((address_space(1))) unsigned int*)(g),
                                     (__attribute__((address_space(3))) unsigned int*)(l), 16, 0, 0);
#else
    *(us8_t*)l = *(const us8_t*)g;
#endif
}

// ---------------- prep: weight transpose (1024 blk) + mask pack (1024 blk) ----------------
__global__ __launch_bounds__(256) void prep_kernel(
    const int* __restrict__ mask,
    const float* __restrict__ w0, const float* __restrict__ w1,
    const float* __restrict__ w2, const float* __restrict__ w3,
    u16* __restrict__ Wt, unsigned* __restrict__ mp)
{
    __shared__ u16 t[64][65];
    const int bid = blockIdx.x, tid = threadIdx.x;
    if (bid < 1024) {
        // weight transpose+convert: fp32 [k][n] -> bf16 [n][k]
        const int z = bid >> 8, rem = bid & 255;
        const float* src = (z == 0) ? w0 : (z == 1) ? w1 : (z == 2) ? w2 : w3;
        u16* dst = Wt + (size_t)z * 1048576;
        const int bk = (rem & 15) * 64, bn = (rem >> 4) * 64;
        const int r = tid >> 2, c4 = tid & 3;
        for (int i = 0; i < 4; i++) {
            float4 vv = *(const float4*)(src + (size_t)(bk + r) * 1024 + bn + c4 * 16 + i * 4);
            t[r][c4 * 16 + i * 4 + 0] = f2bf(vv.x);
            t[r][c4 * 16 + i * 4 + 1] = f2bf(vv.y);
            t[r][c4 * 16 + i * 4 + 2] = f2bf(vv.z);
            t[r][c4 * 16 + i * 4 + 3] = f2bf(vv.w);
        }
        __syncthreads();
        for (int i = 0; i < 2; i++) {
            us8_t w;
            for (int j = 0; j < 8; j++) w[j] = t[c4 * 16 + i * 8 + j][r];
            *(us8_t*)(dst + (size_t)(bn + r) * 1024 + bk + c4 * 16 + i * 8) = w;
        }
    } else {
        // mask pack: 1 bit per key
        const int w = (bid - 1024) * 256 + tid;
        const int* src = mask + (size_t)w * 32;
        unsigned bits = 0u;
        for (int i = 0; i < 32; i += 4) {
            int4 vv = *(const int4*)(src + i);
            bits |= (unsigned)(vv.x != 0) << (i + 0);
            bits |= (unsigned)(vv.y != 0) << (i + 1);
            bits |= (unsigned)(vv.z != 0) << (i + 2);
            bits |= (unsigned)(vv.w != 0) << (i + 3);
        }
        mp[w] = bits;
    }
}

// ---------------- fused QKV projection GEMM: DIRECT-REGISTER, no LDS, no barriers ----------
// Each lane loads its own MFMA fragments straight to VGPRs:
//   A (fp32): rows m0+wm+i*16+l15, k-chunk [k0+quad*8, +8) = 32B contiguous -> cvt bf16
//   W (bf16 [n][k]): rows n0+wn+j*16+l15, same k-chunk = one 16B load
// Values are bit-identical to the old LDS-staged path (same f2bf, same fragment rows).
// 1-deep rotation: extract af/bfr from staged regs, issue loads for t+1, then 16 MFMA
// -> load latency is covered by the MFMA cluster + loop backedge with NO barrier drain
// (the __syncthreads-forces-vmcnt(0) stall of R6 is gone entirely). A-rows reused by
// only 2 waves/block, W-panels by 32 blocks: L2 absorbs the re-reads (34 TB/s headroom).
// z=0: Q -> head-major K-swizzled; z=1: K same; z=2: V -> sigma-permuted+swizzled Vtt.
__global__ __launch_bounds__(256) void qkv_gemm_kernel(
    const float* __restrict__ q, const float* __restrict__ k, const float* __restrict__ v,
    const u16* __restrict__ Wt,
    const float* __restrict__ bq, const float* __restrict__ bk, const float* __restrict__ bv,
    u16* __restrict__ Qh, u16* __restrict__ Kh, u16* __restrict__ Vtt)
{
    const int z = blockIdx.z;
    const float* A = (z == 0) ? q : (z == 1) ? k : v;
    const u16* W = Wt + (size_t)z * 1048576;
    const float* bias = (z == 0) ? bq : (z == 1) ? bk : bv;

    const int m0 = blockIdx.x * 128, n0 = blockIdx.y * 128;
    const int tid = threadIdx.x, lane = tid & 63, wave = tid >> 6;
    const int l15 = lane & 15, quad = lane >> 4;
    const int wm = (wave & 1) * 64, wn = (wave >> 1) * 64;

    const float* arow[4];
    const u16*   wrow[4];
    #pragma unroll
    for (int i = 0; i < 4; i++)
        arow[i] = A + (size_t)(m0 + wm + i * 16 + l15) * 1024 + quad * 8;
    #pragma unroll
    for (int j = 0; j < 4; j++)
        wrow[j] = W + (size_t)(n0 + wn + j * 16 + l15) * 1024 + quad * 8;

    const f32x4_t z4 = {0.f, 0.f, 0.f, 0.f};
    f32x4_t acc[4][4];
    for (int i = 0; i < 4; i++) for (int j = 0; j < 4; j++) acc[i][j] = z4;

    float4 a0r[4], a1r[4];
    us8_t  wr[4];
    auto LD = [&](int t) {
        const int k0 = t * 32;
        #pragma unroll
        for (int i = 0; i < 4; i++) {
            a0r[i] = *(const float4*)(arow[i] + k0);
            a1r[i] = *(const float4*)(arow[i] + k0 + 4);
        }
        #pragma unroll
        for (int j = 0; j < 4; j++) wr[j] = *(const us8_t*)(wrow[j] + k0);
    };

    LD(0);

    for (int t = 0; t < 32; ++t) {
        // extract current fragments from staged regs
        bf16x8_t af[4], bfr[4];
        #pragma unroll
        for (int i = 0; i < 4; i++) {
            us8_t w8;
            w8[0] = f2bf(a0r[i].x); w8[1] = f2bf(a0r[i].y);
            w8[2] = f2bf(a0r[i].z); w8[3] = f2bf(a0r[i].w);
            w8[4] = f2bf(a1r[i].x); w8[5] = f2bf(a1r[i].y);
            w8[6] = f2bf(a1r[i].z); w8[7] = f2bf(a1r[i].w);
            af[i] = __builtin_bit_cast(bf16x8_t, w8);
        }
        #pragma unroll
        for (int j = 0; j < 4; j++) bfr[j] = __builtin_bit_cast(bf16x8_t, wr[j]);

        if (t < 31) LD(t + 1);        // loads fly across the MFMA cluster + backedge

        #pragma unroll
        for (int i = 0; i < 4; i++)
            #pragma unroll
            for (int j = 0; j < 4; j++)
                acc[i][j] = mfma16(af[i], bfr[j], acc[i][j]);
    }

    #pragma unroll
    for (int i = 0; i < 4; i++) {
        const int m = m0 + wm + i * 16 + quad * 4;
        #pragma unroll
        for (int j = 0; j < 4; j++) {
            const int gn = n0 + wn + j * 16 + l15;
            const float bb = bias[gn];
            const int h = gn >> 6, dh = gn & 63;
            if (z < 2) {
                u16* Y = z ? Kh : Qh;
                const int jc = dh >> 3, e = dh & 7;
                #pragma unroll
                for (int r = 0; r < 4; r++) {
                    const int mm = m + r;
                    const int b = mm >> 11, s = mm & 2047;
                    Y[((size_t)(b * 16 + h) * 2048 + s) * 64 + ((jc ^ (s & 7)) * 8) + e] =
                        f2bf(acc[i][j][r] + bb);
                }
            } else {
                const int b = m >> 11, sh = m & 2047, kt2 = sh >> 7, sl = sh & 127;
                const int poslow = ((sl >> 4) & 1) * 4;
                const int chunk = (sl >> 5) * 4 + ((sl >> 2) & 3);
                us4_t w4;
                #pragma unroll
                for (int r = 0; r < 4; r++) w4[r] = f2bf(acc[i][j][r] + bb);
                size_t off = (((size_t)(b * 16 + h) * 16 + kt2) * 8192)
                           + (size_t)dh * 128 + ((chunk ^ (dh & 7)) * 8) + poslow;
                *(us4_t*)&Vtt[off] = w4;
            }
        }
    }
}

// ---------------- output projection GEMM: 64x128 tile, dbuf LDS, ONE barrier/K-step ----------
__global__ __launch_bounds__(256) void out_gemm_kernel(
    const u16* __restrict__ X, const u16* __restrict__ Wt,
    const float* __restrict__ bias, float* __restrict__ Y)
{
    __shared__ __align__(16) u16 As[2][2048];
    __shared__ __align__(16) u16 Bs[2][4096];
    const int m0 = blockIdx.x * 64, n0 = blockIdx.y * 128;
    const int tid = threadIdx.x, lane = tid & 63, wave = tid >> 6;
    const int l15 = lane & 15, quad = lane >> 4;
    const int wm = (wave & 1) * 32, wn = (wave >> 1) * 64;
    const int srow = lane >> 2, scol = (lane & 3) * 8;

    const f32x4_t z4 = {0.f, 0.f, 0.f, 0.f};
    f32x4_t acc[2][4];
    for (int i = 0; i < 2; i++) for (int j = 0; j < 4; j++) acc[i][j] = z4;

    auto stage = [&](int t, int bs) {
        const int k0 = t * 32;
        dma16(X + (size_t)(m0 + wave * 16 + srow) * 1024 + k0 + scol,
              &As[bs][wave * 512 + lane * 8]);
        #pragma unroll
        for (int i = 0; i < 2; i++)
            dma16(Wt + (size_t)(n0 + wave * 32 + i * 16 + srow) * 1024 + k0 + scol,
                  &Bs[bs][wave * 1024 + i * 512 + lane * 8]);
    };

    stage(0, 0);

    for (int t = 0; t < 32; ++t) {
        const int bs = t & 1;
        __syncthreads();              // drains DMA(t); buf bs^1 free (consumed in t-1)
        if (t < 31) stage(t + 1, bs ^ 1);

        bf16x8_t af[2], bfr[4];
        #pragma unroll
        for (int i = 0; i < 2; i++) af[i] = ld_bf8(&As[bs][(wm + i * 16 + l15) * 32 + quad * 8]);
        #pragma unroll
        for (int j = 0; j < 4; j++) bfr[j] = ld_bf8(&Bs[bs][(wn + j * 16 + l15) * 32 + quad * 8]);
        #pragma unroll
        for (int i = 0; i < 2; i++)
            #pragma unroll
            for (int j = 0; j < 4; j++)
                acc[i][j] = mfma16(af[i], bfr[j], acc[i][j]);
    }

    #pragma unroll
    for (int i = 0; i < 2; i++) {
        const int m = m0 + wm + i * 16 + quad * 4;
        #pragma unroll
        for (int j = 0; j < 4; j++) {
            const int gn = n0 + wn + j * 16 + l15;
            const float bb = bias[gn];
            #pragma unroll
            for (int r = 0; r < 4; r++)
                Y[(size_t)(m + r) * 1024 + gn] = acc[i][j][r] + bb;
        }
    }
}

// ---------------- flash attention v8: KVBLK=64, psum via ones-MFMA, nibble-LUT bias ----------
__global__ __launch_bounds__(256, 4) void attn_kernel(
    const u16* __restrict__ Qh, const u16* __restrict__ Kh,
    const u16* __restrict__ Vtt, const unsigned* __restrict__ mp,
    u16* __restrict__ C)
{
    __shared__ __align__(16) u16 Ks[2][4096];
    __shared__ __align__(16) u16 Vs[2][4096];
    __shared__ __align__(16) float4 lut[16];
    const int h = blockIdx.x, qb = blockIdx.y, b = blockIdx.z;
    const int tid = threadIdx.x, lane = tid & 63, wave = tid >> 6;
    const int l15 = lane & 15, quad = lane >> 4;
    const int q0 = qb * 64 + wave * 16;
    const int grow = b * 2048 + q0;
    const size_t headoff = (size_t)(b * 16 + h) * 131072;
    const u16* Qg = Qh + headoff;
    const u16* Kg = Kh + headoff;
    const u16* Vg = Vtt + headoff;

    // bias LUT: entry n, component r = bit r of n ? -1e5 : -12*log2e
    if (tid < 16) {
        float4 bv4;
        bv4.x = (tid & 1) ? -1e5f : -17.312340491f;
        bv4.y = (tid & 2) ? -1e5f : -17.312340491f;
        bv4.z = (tid & 4) ? -1e5f : -17.312340491f;
        bv4.w = (tid & 8) ? -1e5f : -17.312340491f;
        lut[tid] = bv4;
    }

    // Q fragments for this wave's 16 q-rows (dims 0-31, 32-63), unswizzled on load
    bf16x8_t aq[2];
    #pragma unroll
    for (int ks = 0; ks < 2; ks++)
        aq[ks] = ld_bf8(Qg + (size_t)(q0 + l15) * 64 + (((ks * 4 + quad) ^ (l15 & 7)) * 8));

    // B-fragment of all-ones (bf16 1.0 = 0x3F80) for the psum MFMA
    us8_t ones_u;
    #pragma unroll
    for (int i = 0; i < 8; i++) ones_u[i] = 0x3F80;
    const bf16x8_t ones = __builtin_bit_cast(bf16x8_t, ones_u);

    const f32x4_t z4 = {0.f, 0.f, 0.f, 0.f};
    f32x4_t o[4];
    #pragma unroll
    for (int i = 0; i < 4; i++) o[i] = z4;
    f32x4_t osum = z4;   // osum[r] = sum_k P[qrow=quad*4+r][k] (same in all lanes' cols)

    const int swA = (quad ^ (l15 & 7)) * 8;
    const int swB = ((4 + quad) ^ (l15 & 7)) * 8;

    const unsigned* mrow = mp + (size_t)(b * 2048 + q0 + l15) * 64;

    // stage 64-key tile kt into buffer bs: each wave DMAs 16 keys of K + 16 d-rows of V (4KB)
    auto stage = [&](int kt, int bs) {
        const u16* kg = Kg + kt * 4096 + wave * 1024;
        const u16* vg = Vg + (kt >> 1) * 8192 + (kt & 1) * 64;
        u16* kl = &Ks[bs][wave * 1024];
        u16* vl = &Vs[bs][wave * 1024];
        #pragma unroll
        for (int i = 0; i < 2; i++) {
            dma16(kg + i * 512 + lane * 8, kl + i * 512 + lane * 8);
            dma16(vg + (size_t)(wave * 16 + i * 8 + (lane >> 3)) * 128 + (lane & 7) * 8,
                  vl + i * 512 + lane * 8);
        }
    };

    stage(0, 0);

    for (int kt = 0; kt < 32; ++kt) {
        const int bs = kt & 1;
        __syncthreads();              // drains DMA(kt); buf bs^1 is free (consumed in kt-1)
        if (kt < 31) stage(kt + 1, bs ^ 1);

        const int2 mv = *(const int2*)(mrow + kt * 2);

        // --- S^T = K.Q^T : rows=keys (64), cols=qrows (16) ---
        f32x4_t sc[4];
        __builtin_amdgcn_s_setprio(1);
        #pragma unroll
        for (int st = 0; st < 4; st++) {
            const u16* kp = &Ks[bs][(st * 16 + l15) * 64];
            bf16x8_t k0 = ld_bf8(kp + swA);
            bf16x8_t k1 = ld_bf8(kp + swB);
            sc[st] = mfma16(k1, aq[1], mfma16(k0, aq[0], z4));
        }
        __builtin_amdgcn_s_setprio(0);

        // --- fixed-max softmax (exp2, log2e pre-folded), bias via nibble LUT ---
        us8_t ap[2];
        #pragma unroll
        for (int st = 0; st < 4; st++) {
            const unsigned w = (st < 2) ? (unsigned)mv.x : (unsigned)mv.y;
            const int nib = (w >> (((st & 1) << 4) + quad * 4)) & 15;
            const float4 b4 = lut[nib];
            ap[st >> 1][((st & 1) << 2) + 0] = f2bf(exp2_fast(fmaf(sc[st][0], 0.18033688011f, b4.x)));
            ap[st >> 1][((st & 1) << 2) + 1] = f2bf(exp2_fast(fmaf(sc[st][1], 0.18033688011f, b4.y)));
            ap[st >> 1][((st & 1) << 2) + 2] = f2bf(exp2_fast(fmaf(sc[st][2], 0.18033688011f, b4.z)));
            ap[st >> 1][((st & 1) << 2) + 3] = f2bf(exp2_fast(fmaf(sc[st][3], 0.18033688011f, b4.w)));
        }

        // --- PV: A-frag from registers, B-frag from sigma-permuted V half-tile ---
        __builtin_amdgcn_s_setprio(1);
        #pragma unroll
        for (int c = 0; c < 2; c++) {
            bf16x8_t a = __builtin_bit_cast(bf16x8_t, ap[c]);
            osum = mfma16(a, ones, osum);   // row-sum of P into the matrix pipe
            #pragma unroll
            for (int nt = 0; nt < 4; nt++) {
                bf16x8_t bv = ld_bf8(&Vs[bs][(nt * 16 + l15) * 64
                                             + (((c * 4 + quad) ^ (l15 & 7)) * 8)]);
                o[nt] = mfma16(a, bv, o[nt]);
            }
        }
        __builtin_amdgcn_s_setprio(0);
    }

    // osum[r] = denominator for q-row (quad*4+r), identical across lanes -> no shuffles
    #pragma unroll
    for (int r = 0; r < 4; r++) {
        const float invl = 1.0f / osum[r];
        const int row = grow + quad * 4 + r;
        #pragma unroll
        for (int nt = 0; nt < 4; nt++)
            C[(size_t)row * 1024 + h * 64 + nt * 16 + l15] = f2bf(o[nt][r] * invl);
    }
}

extern "C" void kernel_launch(void* const* d_in, const int* in_sizes, int n_in,
                              void* d_out, int out_size, void* d_ws, size_t ws_size,
                              hipStream_t stream) {
    const float* q    = (const float*)d_in[0];
    const float* k    = (const float*)d_in[1];
    const float* v    = (const float*)d_in[2];
    const int*   mask = (const int*)d_in[3];
    const float* wq   = (const float*)d_in[4];
    const float* bq   = (const float*)d_in[5];
    const float* wk   = (const float*)d_in[6];
    const float* bk   = (const float*)d_in[7];
    const float* wv   = (const float*)d_in[8];
    const float* bv   = (const float*)d_in[9];
    const float* wo   = (const float*)d_in[10];
    const float* bo   = (const float*)d_in[11];
    float* out = (float*)d_out;

    char* ws = (char*)d_ws;
    const size_t MB = 1ull << 20;
    u16* Wt      = (u16*)(ws);              // 8 MB: 4 weights bf16 [n][k]
    u16* Qhh     = (u16*)(ws + 8 * MB);     // 8 MB head-major swizzled
    u16* Khh     = (u16*)(ws + 16 * MB);    // 8 MB head-major swizzled
    u16* Vtt     = (u16*)(ws + 24 * MB);    // 8 MB tiled sigma-permuted swizzled
    u16* CT      = (u16*)(ws + 32 * MB);    // 8 MB attention output bf16
    unsigned* mp = (unsigned*)(ws + 40 * MB); // 1 MB

    prep_kernel<<<dim3(2048), 256, 0, stream>>>(
        mask, wq, wk, wv, wo, Wt, mp);

    qkv_gemm_kernel<<<dim3(32, 8, 3), 256, 0, stream>>>(
        q, k, v, Wt, bq, bk, bv, Qhh, Khh, Vtt);

    attn_kernel<<<dim3(16, 32, 2), 256, 0, stream>>>(Qhh, Khh, Vtt, mp, CT);

    out_gemm_kernel<<<dim3(64, 8), 256, 0, stream>>>(CT, Wt + 3ull * 1048576, bo, out);
}

// Round 8
// 266.790 us; speedup vs baseline: 1.2452x; 1.2452x over previous
//
#include <hip/hip_runtime.h>

typedef unsigned short u16;
typedef __bf16 bf16x8_t __attribute__((ext_vector_type(8)));
typedef float  f32x4_t  __attribute__((ext_vector_type(4)));
typedef u16    us8_t    __attribute__((ext_vector_type(8)));
typedef u16    us4_t    __attribute__((ext_vector_type(4)));

__device__ __forceinline__ u16 f2bf(float f) {
    __bf16 h = (__bf16)f;
    return __builtin_bit_cast(u16, h);
}
__device__ __forceinline__ bf16x8_t ld_bf8(const u16* p) {
    us8_t u = *(const us8_t*)p;
    return __builtin_bit_cast(bf16x8_t, u);
}
__device__ __forceinline__ f32x4_t mfma16(bf16x8_t a, bf16x8_t b, f32x4_t c) {
    return __builtin_amdgcn_mfma_f32_16x16x32_bf16(a, b, c, 0, 0, 0);
}
__device__ __forceinline__ float exp2_fast(float x) {
#if __has_builtin(__builtin_amdgcn_exp2f)
    return __builtin_amdgcn_exp2f(x);
#else
    return exp2f(x);
#endif
}

// async global->LDS, 16B per lane. LDS dest MUST be base + lane*16 (wave-uniform base).
__device__ __forceinline__ void dma16(const void* g, void* l) {
#if __has_builtin(__builtin_amdgcn_global_load_lds)
    __builtin_amdgcn_global_load_lds((const __attribute__((address_space(1))) unsigned int*)(g),
                                     (__attribute__((address_space(3))) unsigned int*)(l), 16, 0, 0);
#else
    *(us8_t*)l = *(const us8_t*)g;
#endif
}

// ---------------- prep: weight transpose (1024 blk) + mask pack (1024 blk) ----------------
// q/k/v fp32->bf16 cvt happens inside qkv_gemm's fp32 LDS staging (no separate pass).
__global__ __launch_bounds__(256) void prep_kernel(
    const int* __restrict__ mask,
    const float* __restrict__ w0, const float* __restrict__ w1,
    const float* __restrict__ w2, const float* __restrict__ w3,
    u16* __restrict__ Wt, unsigned* __restrict__ mp)
{
    __shared__ u16 t[64][65];
    const int bid = blockIdx.x, tid = threadIdx.x;
    if (bid < 1024) {
        // weight transpose+convert: fp32 [k][n] -> bf16 [n][k]
        const int z = bid >> 8, rem = bid & 255;
        const float* src = (z == 0) ? w0 : (z == 1) ? w1 : (z == 2) ? w2 : w3;
        u16* dst = Wt + (size_t)z * 1048576;
        const int bk = (rem & 15) * 64, bn = (rem >> 4) * 64;
        const int r = tid >> 2, c4 = tid & 3;
        for (int i = 0; i < 4; i++) {
            float4 vv = *(const float4*)(src + (size_t)(bk + r) * 1024 + bn + c4 * 16 + i * 4);
            t[r][c4 * 16 + i * 4 + 0] = f2bf(vv.x);
            t[r][c4 * 16 + i * 4 + 1] = f2bf(vv.y);
            t[r][c4 * 16 + i * 4 + 2] = f2bf(vv.z);
            t[r][c4 * 16 + i * 4 + 3] = f2bf(vv.w);
        }
        __syncthreads();
        for (int i = 0; i < 2; i++) {
            us8_t w;
            for (int j = 0; j < 8; j++) w[j] = t[c4 * 16 + i * 8 + j][r];
            *(us8_t*)(dst + (size_t)(bn + r) * 1024 + bk + c4 * 16 + i * 8) = w;
        }
    } else {
        // mask pack: 1 bit per key
        const int w = (bid - 1024) * 256 + tid;
        const int* src = mask + (size_t)w * 32;
        unsigned bits = 0u;
        for (int i = 0; i < 32; i += 4) {
            int4 vv = *(const int4*)(src + i);
            bits |= (unsigned)(vv.x != 0) << (i + 0);
            bits |= (unsigned)(vv.y != 0) << (i + 1);
            bits |= (unsigned)(vv.z != 0) << (i + 2);
            bits |= (unsigned)(vv.w != 0) << (i + 3);
        }
        mp[w] = bits;
    }
}

// ---------------- fused QKV projection GEMM: R2 structure, A staged as fp32 via DMA ----------
// EXACT R2 schedule (stage -> sync -> 16 MFMA -> sync, single-buffered, global_load_lds).
// Only change vs R2: A is the ORIGINAL fp32 q/k/v, staged into a 16KB chunk-swizzled
// fp32 LDS tile (T21: linear LDS dest + inverse-swizzled GLOBAL source + swizzled read):
//   stage:  row = wave*32+i*8+(lane>>3), slot = lane&7 -> global chunk = slot ^ (row&7)
//   read:   row r needs global chunks {2q, 2q+1} -> LDS slots {2q^(r&7), (2q+1)^(r&7)}
// cvt f32->bf16 at fragment build (same f2bf RNE => bit-identical MFMA inputs to R2).
// Swizzle makes the A ds_read ~2-way bank aliased (free, m136) vs R2's 8-way.
// z=0: Q -> head-major K-swizzled; z=1: K same; z=2: V -> sigma-permuted+swizzled Vtt.
__global__ __launch_bounds__(256) void qkv_gemm_kernel(
    const float* __restrict__ q, const float* __restrict__ k, const float* __restrict__ v,
    const u16* __restrict__ Wt,
    const float* __restrict__ bq, const float* __restrict__ bk, const float* __restrict__ bv,
    u16* __restrict__ Qh, u16* __restrict__ Kh, u16* __restrict__ Vtt)
{
    __shared__ __align__(16) float Af[4096];   // 16KB: [128 rows][32 f32], chunk-swizzled
    __shared__ __align__(16) u16   Bs[4096];   // 8KB:  [128 rows][32 bf16] (R2 layout)
    const int z = blockIdx.z;
    const float* A = (z == 0) ? q : (z == 1) ? k : v;
    const u16* W = Wt + (size_t)z * 1048576;
    const float* bias = (z == 0) ? bq : (z == 1) ? bk : bv;

    const int m0 = blockIdx.x * 128, n0 = blockIdx.y * 128;
    const int tid = threadIdx.x, lane = tid & 63, wave = tid >> 6;
    const int l15 = lane & 15, quad = lane >> 4;
    const int wm = (wave & 1) * 64, wn = (wave >> 1) * 64;
    const int srow = lane >> 2, scol = (lane & 3) * 8;     // B staging (R2)
    const int arl = lane >> 3, aslot = lane & 7;           // A staging

    const f32x4_t z4 = {0.f, 0.f, 0.f, 0.f};
    f32x4_t acc[4][4];
    for (int i = 0; i < 4; i++) for (int j = 0; j < 4; j++) acc[i][j] = z4;

    for (int k0 = 0; k0 < 1024; k0 += 32) {
        // --- stage A: 4x dma16 of fp32, inverse-swizzled global source, linear LDS dest ---
        #pragma unroll
        for (int i = 0; i < 4; i++) {
            const int row = wave * 32 + i * 8 + arl;
            const int gch = aslot ^ (row & 7);
            dma16(A + (size_t)(m0 + row) * 1024 + k0 + gch * 4,
                  &Af[wave * 1024 + i * 256 + lane * 4]);
        }
        // --- stage B: 2x dma16 of bf16 (exact R2 path) ---
        #pragma unroll
        for (int i = 0; i < 2; i++)
            dma16(W + (size_t)(n0 + wave * 32 + i * 16 + srow) * 1024 + k0 + scol,
                  &Bs[wave * 1024 + i * 512 + lane * 8]);
        __syncthreads();

        bf16x8_t af[4], bfr[4];
        #pragma unroll
        for (int i = 0; i < 4; i++) {
            const int r = wm + i * 16 + l15;
            const f32x4_t lo = *(const f32x4_t*)&Af[r * 32 + ((2 * quad) ^ (r & 7)) * 4];
            const f32x4_t hi = *(const f32x4_t*)&Af[r * 32 + ((2 * quad + 1) ^ (r & 7)) * 4];
            us8_t w8;
            w8[0] = f2bf(lo[0]); w8[1] = f2bf(lo[1]); w8[2] = f2bf(lo[2]); w8[3] = f2bf(lo[3]);
            w8[4] = f2bf(hi[0]); w8[5] = f2bf(hi[1]); w8[6] = f2bf(hi[2]); w8[7] = f2bf(hi[3]);
            af[i] = __builtin_bit_cast(bf16x8_t, w8);
        }
        #pragma unroll
        for (int j = 0; j < 4; j++) bfr[j] = ld_bf8(&Bs[(wn + j * 16 + l15) * 32 + quad * 8]);
        #pragma unroll
        for (int i = 0; i < 4; i++)
            #pragma unroll
            for (int j = 0; j < 4; j++)
                acc[i][j] = mfma16(af[i], bfr[j], acc[i][j]);
        __syncthreads();
    }

    #pragma unroll
    for (int i = 0; i < 4; i++) {
        const int m = m0 + wm + i * 16 + quad * 4;
        #pragma unroll
        for (int j = 0; j < 4; j++) {
            const int gn = n0 + wn + j * 16 + l15;
            const float bb = bias[gn];
            const int h = gn >> 6, dh = gn & 63;
            if (z < 2) {
                u16* Y = z ? Kh : Qh;
                const int jc = dh >> 3, e = dh & 7;
                #pragma unroll
                for (int r = 0; r < 4; r++) {
                    const int mm = m + r;
                    const int b = mm >> 11, s = mm & 2047;
                    Y[((size_t)(b * 16 + h) * 2048 + s) * 64 + ((jc ^ (s & 7)) * 8) + e] =
                        f2bf(acc[i][j][r] + bb);
                }
            } else {
                const int b = m >> 11, sh = m & 2047, kt2 = sh >> 7, sl = sh & 127;
                const int poslow = ((sl >> 4) & 1) * 4;
                const int chunk = (sl >> 5) * 4 + ((sl >> 2) & 3);
                us4_t w4;
                #pragma unroll
                for (int r = 0; r < 4; r++) w4[r] = f2bf(acc[i][j][r] + bb);
                size_t off = (((size_t)(b * 16 + h) * 16 + kt2) * 8192)
                           + (size_t)dh * 128 + ((chunk ^ (dh & 7)) * 8) + poslow;
                *(us4_t*)&Vtt[off] = w4;
            }
        }
    }
}

// ---------------- output projection GEMM: 64x128 tile (exact R0-R2 version) ----------------
__global__ __launch_bounds__(256) void out_gemm_kernel(
    const u16* __restrict__ X, const u16* __restrict__ Wt,
    const float* __restrict__ bias, float* __restrict__ Y)
{
    __shared__ __align__(16) u16 As[2048];
    __shared__ __align__(16) u16 Bs[4096];
    const int m0 = blockIdx.x * 64, n0 = blockIdx.y * 128;
    const int tid = threadIdx.x, lane = tid & 63, wave = tid >> 6;
    const int l15 = lane & 15, quad = lane >> 4;
    const int wm = (wave & 1) * 32, wn = (wave >> 1) * 64;
    const int srow = lane >> 2, scol = (lane & 3) * 8;

    const f32x4_t z4 = {0.f, 0.f, 0.f, 0.f};
    f32x4_t acc[2][4];
    for (int i = 0; i < 2; i++) for (int j = 0; j < 4; j++) acc[i][j] = z4;

    for (int k0 = 0; k0 < 1024; k0 += 32) {
        dma16(X + (size_t)(m0 + wave * 16 + srow) * 1024 + k0 + scol,
              &As[wave * 512 + lane * 8]);
        #pragma unroll
        for (int i = 0; i < 2; i++)
            dma16(Wt + (size_t)(n0 + wave * 32 + i * 16 + srow) * 1024 + k0 + scol,
                  &Bs[wave * 1024 + i * 512 + lane * 8]);
        __syncthreads();
        bf16x8_t af[2], bfr[4];
        #pragma unroll
        for (int i = 0; i < 2; i++) af[i] = ld_bf8(&As[(wm + i * 16 + l15) * 32 + quad * 8]);
        #pragma unroll
        for (int j = 0; j < 4; j++) bfr[j] = ld_bf8(&Bs[(wn + j * 16 + l15) * 32 + quad * 8]);
        #pragma unroll
        for (int i = 0; i < 2; i++)
            #pragma unroll
            for (int j = 0; j < 4; j++)
                acc[i][j] = mfma16(af[i], bfr[j], acc[i][j]);
        __syncthreads();
    }

    #pragma unroll
    for (int i = 0; i < 2; i++) {
        const int m = m0 + wm + i * 16 + quad * 4;
        #pragma unroll
        for (int j = 0; j < 4; j++) {
            const int gn = n0 + wn + j * 16 + l15;
            const float bb = bias[gn];
            #pragma unroll
            for (int r = 0; r < 4; r++)
                Y[(size_t)(m + r) * 1024 + gn] = acc[i][j][r] + bb;
        }
    }
}

// ---------------- flash attention v8: KVBLK=64, psum via ones-MFMA, nibble-LUT bias ----------
// (verified correct in R6 and R7)
__global__ __launch_bounds__(256, 4) void attn_kernel(
    const u16* __restrict__ Qh, const u16* __restrict__ Kh,
    const u16* __restrict__ Vtt, const unsigned* __restrict__ mp,
    u16* __restrict__ C)
{
    __shared__ __align__(16) u16 Ks[2][4096];
    __shared__ __align__(16) u16 Vs[2][4096];
    __shared__ __align__(16) float4 lut[16];
    const int h = blockIdx.x, qb = blockIdx.y, b = blockIdx.z;
    const int tid = threadIdx.x, lane = tid & 63, wave = tid >> 6;
    const int l15 = lane & 15, quad = lane >> 4;
    const int q0 = qb * 64 + wave * 16;
    const int grow = b * 2048 + q0;
    const size_t headoff = (size_t)(b * 16 + h) * 131072;
    const u16* Qg = Qh + headoff;
    const u16* Kg = Kh + headoff;
    const u16* Vg = Vtt + headoff;

    // bias LUT: entry n, component r = bit r of n ? -1e5 : -12*log2e
    if (tid < 16) {
        float4 bv4;
        bv4.x = (tid & 1) ? -1e5f : -17.312340491f;
        bv4.y = (tid & 2) ? -1e5f : -17.312340491f;
        bv4.z = (tid & 4) ? -1e5f : -17.312340491f;
        bv4.w = (tid & 8) ? -1e5f : -17.312340491f;
        lut[tid] = bv4;
    }

    // Q fragments for this wave's 16 q-rows (dims 0-31, 32-63), unswizzled on load
    bf16x8_t aq[2];
    #pragma unroll
    for (int ks = 0; ks < 2; ks++)
        aq[ks] = ld_bf8(Qg + (size_t)(q0 + l15) * 64 + (((ks * 4 + quad) ^ (l15 & 7)) * 8));

    // B-fragment of all-ones (bf16 1.0 = 0x3F80) for the psum MFMA
    us8_t ones_u;
    #pragma unroll
    for (int i = 0; i < 8; i++) ones_u[i] = 0x3F80;
    const bf16x8_t ones = __builtin_bit_cast(bf16x8_t, ones_u);

    const f32x4_t z4 = {0.f, 0.f, 0.f, 0.f};
    f32x4_t o[4];
    #pragma unroll
    for (int i = 0; i < 4; i++) o[i] = z4;
    f32x4_t osum = z4;   // osum[r] = sum_k P[qrow=quad*4+r][k] (same in all lanes' cols)

    const int swA = (quad ^ (l15 & 7)) * 8;
    const int swB = ((4 + quad) ^ (l15 & 7)) * 8;

    const unsigned* mrow = mp + (size_t)(b * 2048 + q0 + l15) * 64;

    // stage 64-key tile kt into buffer bs: each wave DMAs 16 keys of K + 16 d-rows of V (4KB)
    auto stage = [&](int kt, int bs) {
        const u16* kg = Kg + kt * 4096 + wave * 1024;
        const u16* vg = Vg + (kt >> 1) * 8192 + (kt & 1) * 64;
        u16* kl = &Ks[bs][wave * 1024];
        u16* vl = &Vs[bs][wave * 1024];
        #pragma unroll
        for (int i = 0; i < 2; i++) {
            dma16(kg + i * 512 + lane * 8, kl + i * 512 + lane * 8);
            dma16(vg + (size_t)(wave * 16 + i * 8 + (lane >> 3)) * 128 + (lane & 7) * 8,
                  vl + i * 512 + lane * 8);
        }
    };

    stage(0, 0);

    for (int kt = 0; kt < 32; ++kt) {
        const int bs = kt & 1;
        __syncthreads();              // drains DMA(kt); buf bs^1 is free (consumed in kt-1)
        if (kt < 31) stage(kt + 1, bs ^ 1);

        const int2 mv = *(const int2*)(mrow + kt * 2);

        // --- S^T = K.Q^T : rows=keys (64), cols=qrows (16) ---
        f32x4_t sc[4];
        __builtin_amdgcn_s_setprio(1);
        #pragma unroll
        for (int st = 0; st < 4; st++) {
            const u16* kp = &Ks[bs][(st * 16 + l15) * 64];
            bf16x8_t k0 = ld_bf8(kp + swA);
            bf16x8_t k1 = ld_bf8(kp + swB);
            sc[st] = mfma16(k1, aq[1], mfma16(k0, aq[0], z4));
        }
        __builtin_amdgcn_s_setprio(0);

        // --- fixed-max softmax (exp2, log2e pre-folded), bias via nibble LUT ---
        us8_t ap[2];
        #pragma unroll
        for (int st = 0; st < 4; st++) {
            const unsigned w = (st < 2) ? (unsigned)mv.x : (unsigned)mv.y;
            const int nib = (w >> (((st & 1) << 4) + quad * 4)) & 15;
            const float4 b4 = lut[nib];
            ap[st >> 1][((st & 1) << 2) + 0] = f2bf(exp2_fast(fmaf(sc[st][0], 0.18033688011f, b4.x)));
            ap[st >> 1][((st & 1) << 2) + 1] = f2bf(exp2_fast(fmaf(sc[st][1], 0.18033688011f, b4.y)));
            ap[st >> 1][((st & 1) << 2) + 2] = f2bf(exp2_fast(fmaf(sc[st][2], 0.18033688011f, b4.z)));
            ap[st >> 1][((st & 1) << 2) + 3] = f2bf(exp2_fast(fmaf(sc[st][3], 0.18033688011f, b4.w)));
        }

        // --- PV: A-frag from registers, B-frag from sigma-permuted V half-tile ---
        __builtin_amdgcn_s_setprio(1);
        #pragma unroll
        for (int c = 0; c < 2; c++) {
            bf16x8_t a = __builtin_bit_cast(bf16x8_t, ap[c]);
            osum = mfma16(a, ones, osum);   // row-sum of P into the matrix pipe
            #pragma unroll
            for (int nt = 0; nt < 4; nt++) {
                bf16x8_t bv = ld_bf8(&Vs[bs][(nt * 16 + l15) * 64
                                             + (((c * 4 + quad) ^ (l15 & 7)) * 8)]);
                o[nt] = mfma16(a, bv, o[nt]);
            }
        }
        __builtin_amdgcn_s_setprio(0);
    }

    // osum[r] = denominator for q-row (quad*4+r), identical across lanes -> no shuffles
    #pragma unroll
    for (int r = 0; r < 4; r++) {
        const float invl = 1.0f / osum[r];
        const int row = grow + quad * 4 + r;
        #pragma unroll
        for (int nt = 0; nt < 4; nt++)
            C[(size_t)row * 1024 + h * 64 + nt * 16 + l15] = f2bf(o[nt][r] * invl);
    }
}

extern "C" void kernel_launch(void* const* d_in, const int* in_sizes, int n_in,
                              void* d_out, int out_size, void* d_ws, size_t ws_size,
                              hipStream_t stream) {
    const float* q    = (const float*)d_in[0];
    const float* k    = (const float*)d_in[1];
    const float* v    = (const float*)d_in[2];
    const int*   mask = (const int*)d_in[3];
    const float* wq   = (const float*)d_in[4];
    const float* bq   = (const float*)d_in[5];
    const float* wk   = (const float*)d_in[6];
    const float* bk   = (const float*)d_in[7];
    const float* wv   = (const float*)d_in[8];
    const float* bv   = (const float*)d_in[9];
    const float* wo   = (const float*)d_in[10];
    const float* bo   = (const float*)d_in[11];
    float* out = (float*)d_out;

    char* ws = (char*)d_ws;
    const size_t MB = 1ull << 20;
    u16* Wt      = (u16*)(ws);              // 8 MB: 4 weights bf16 [n][k]
    u16* Qhh     = (u16*)(ws + 8 * MB);     // 8 MB head-major swizzled
    u16* Khh     = (u16*)(ws + 16 * MB);    // 8 MB head-major swizzled
    u16* Vtt     = (u16*)(ws + 24 * MB);    // 8 MB tiled sigma-permuted swizzled
    u16* CT      = (u16*)(ws + 32 * MB);    // 8 MB attention output bf16
    unsigned* mp = (unsigned*)(ws + 40 * MB); // 1 MB

    prep_kernel<<<dim3(2048), 256, 0, stream>>>(
        mask, wq, wk, wv, wo, Wt, mp);

    qkv_gemm_kernel<<<dim3(32, 8, 3), 256, 0, stream>>>(
        q, k, v, Wt, bq, bk, bv, Qhh, Khh, Vtt);

    attn_kernel<<<dim3(16, 32, 2), 256, 0, stream>>>(Qhh, Khh, Vtt, mp, CT);

    out_gemm_kernel<<<dim3(64, 8), 256, 0, stream>>>(CT, Wt + 3ull * 1048576, bo, out);
}

// Round 9
// 261.030 us; speedup vs baseline: 1.2726x; 1.0221x over previous
//
#include <hip/hip_runtime.h>

typedef unsigned short u16;
typedef __bf16 bf16x8_t __attribute__((ext_vector_type(8)));
typedef float  f32x4_t  __attribute__((ext_vector_type(4)));
typedef u16    us8_t    __attribute__((ext_vector_type(8)));
typedef u16    us4_t    __attribute__((ext_vector_type(4)));

__device__ __forceinline__ u16 f2bf(float f) {
    __bf16 h = (__bf16)f;
    return __builtin_bit_cast(u16, h);
}
__device__ __forceinline__ bf16x8_t ld_bf8(const u16* p) {
    us8_t u = *(const us8_t*)p;
    return __builtin_bit_cast(bf16x8_t, u);
}
__device__ __forceinline__ f32x4_t mfma16(bf16x8_t a, bf16x8_t b, f32x4_t c) {
    return __builtin_amdgcn_mfma_f32_16x16x32_bf16(a, b, c, 0, 0, 0);
}
__device__ __forceinline__ float exp2_fast(float x) {
#if __has_builtin(__builtin_amdgcn_exp2f)
    return __builtin_amdgcn_exp2f(x);
#else
    return exp2f(x);
#endif
}

// async global->LDS, 16B per lane. LDS dest MUST be base + lane*16 (wave-uniform base).
__device__ __forceinline__ void dma16(const void* g, void* l) {
#if __has_builtin(__builtin_amdgcn_global_load_lds)
    __builtin_amdgcn_global_load_lds((const __attribute__((address_space(1))) unsigned int*)(g),
                                     (__attribute__((address_space(3))) unsigned int*)(l), 16, 0, 0);
#else
    *(us8_t*)l = *(const us8_t*)g;
#endif
}

// ---------------- fused prep: cvt (6144 blk) + weight transpose (1024) + mask pack (1024) ----
// (exact R0-R5 version: separate bf16 cvt pass is the best-measured A-path for qkv)
__global__ __launch_bounds__(256) void prep_kernel(
    const float* __restrict__ q, const float* __restrict__ k, const float* __restrict__ v,
    const int* __restrict__ mask,
    const float* __restrict__ w0, const float* __restrict__ w1,
    const float* __restrict__ w2, const float* __restrict__ w3,
    u16* __restrict__ Qc, u16* __restrict__ Kc, u16* __restrict__ Vc,
    u16* __restrict__ Wt, unsigned* __restrict__ mp)
{
    __shared__ u16 t[64][65];
    const int bid = blockIdx.x, tid = threadIdx.x;
    if (bid < 6144) {
        // fp32 -> bf16 convert of q,k,v
        const int z = bid >> 11, x = bid & 2047;
        const float* src = (z == 0) ? q : (z == 1) ? k : v;
        u16* dst = (z == 0) ? Qc : (z == 1) ? Kc : Vc;
        const size_t i = ((size_t)x * 256 + tid) * 8;
        float4 a = *(const float4*)(src + i);
        float4 b = *(const float4*)(src + i + 4);
        us8_t w;
        w[0] = f2bf(a.x); w[1] = f2bf(a.y); w[2] = f2bf(a.z); w[3] = f2bf(a.w);
        w[4] = f2bf(b.x); w[5] = f2bf(b.y); w[6] = f2bf(b.z); w[7] = f2bf(b.w);
        *(us8_t*)(dst + i) = w;
    } else if (bid < 7168) {
        // weight transpose+convert: fp32 [k][n] -> bf16 [n][k]
        const int r2 = bid - 6144;
        const int z = r2 >> 8, rem = r2 & 255;
        const float* src = (z == 0) ? w0 : (z == 1) ? w1 : (z == 2) ? w2 : w3;
        u16* dst = Wt + (size_t)z * 1048576;
        const int bk = (rem & 15) * 64, bn = (rem >> 4) * 64;
        const int r = tid >> 2, c4 = tid & 3;
        for (int i = 0; i < 4; i++) {
            float4 vv = *(const float4*)(src + (size_t)(bk + r) * 1024 + bn + c4 * 16 + i * 4);
            t[r][c4 * 16 + i * 4 + 0] = f2bf(vv.x);
            t[r][c4 * 16 + i * 4 + 1] = f2bf(vv.y);
            t[r][c4 * 16 + i * 4 + 2] = f2bf(vv.z);
            t[r][c4 * 16 + i * 4 + 3] = f2bf(vv.w);
        }
        __syncthreads();
        for (int i = 0; i < 2; i++) {
            us8_t w;
            for (int j = 0; j < 8; j++) w[j] = t[c4 * 16 + i * 8 + j][r];
            *(us8_t*)(dst + (size_t)(bn + r) * 1024 + bk + c4 * 16 + i * 8) = w;
        }
    } else {
        // mask pack: 1 bit per key
        const int w = (bid - 7168) * 256 + tid;
        const int* src = mask + (size_t)w * 32;
        unsigned bits = 0u;
        for (int i = 0; i < 32; i += 4) {
            int4 vv = *(const int4*)(src + i);
            bits |= (unsigned)(vv.x != 0) << (i + 0);
            bits |= (unsigned)(vv.y != 0) << (i + 1);
            bits |= (unsigned)(vv.z != 0) << (i + 2);
            bits |= (unsigned)(vv.w != 0) << (i + 3);
        }
        mp[w] = bits;
    }
}

// ---------------- fused QKV projection GEMM: BK=64, chunk-XOR-swizzled LDS ----------------
// R2 schedule (stage -> sync -> MFMA -> sync) with BK doubled 32->64: 16 K-steps instead
// of 32 -> HALF the barrier drains, 2x MFMA (32) per drain. Tiles [128][64] bf16 (16KB
// each, 32KB total -> 3 blocks/CU by grid). Both tiles chunk-XOR swizzled (T21, same
// involution as the attn Qh/Kh layout): stage writes 16B chunk (lane&7) from global
// chunk (lane&7)^(row&7); read fetches chunk (kk*4+quad)^(row&7). This keeps the
// ds_read_b128 at the structural-minimum 8 lanes/slot (row stride 128B = full wrap).
// z=0: Q -> head-major K-swizzled; z=1: K same; z=2: V -> sigma-permuted+swizzled Vtt.
__global__ __launch_bounds__(256) void qkv_gemm_kernel(
    const u16* __restrict__ Qc, const u16* __restrict__ Kc, const u16* __restrict__ Vc,
    const u16* __restrict__ Wt,
    const float* __restrict__ bq, const float* __restrict__ bk, const float* __restrict__ bv,
    u16* __restrict__ Qh, u16* __restrict__ Kh, u16* __restrict__ Vtt)
{
    __shared__ __align__(16) u16 As[8192];   // [128 rows][64 k] swizzled
    __shared__ __align__(16) u16 Bs[8192];
    const int z = blockIdx.z;
    const u16* A = (z == 0) ? Qc : (z == 1) ? Kc : Vc;
    const u16* W = Wt + (size_t)z * 1048576;
    const float* bias = (z == 0) ? bq : (z == 1) ? bk : bv;

    const int m0 = blockIdx.x * 128, n0 = blockIdx.y * 128;
    const int tid = threadIdx.x, lane = tid & 63, wave = tid >> 6;
    const int l15 = lane & 15, quad = lane >> 4;
    const int wm = (wave & 1) * 64, wn = (wave >> 1) * 64;
    const int lr8 = lane >> 3;                 // staging row within 8-row group
    const int lc8 = lane & 7;                  // staging chunk slot

    const f32x4_t z4 = {0.f, 0.f, 0.f, 0.f};
    f32x4_t acc[4][4];
    for (int i = 0; i < 4; i++) for (int j = 0; j < 4; j++) acc[i][j] = z4;

    for (int t = 0; t < 16; ++t) {
        const int k0 = t * 64;
        // --- stage: 4 dma16 A + 4 dma16 B per lane; source chunk inverse-swizzled ---
        #pragma unroll
        for (int i = 0; i < 4; i++) {
            const int row = wave * 32 + i * 8 + lr8;           // 0..127
            const int gc  = (lc8 ^ (row & 7)) * 8;             // global k-chunk offset
            dma16(A + (size_t)(m0 + row) * 1024 + k0 + gc,
                  &As[(wave * 32 + i * 8) * 64 + lane * 8]);
            dma16(W + (size_t)(n0 + row) * 1024 + k0 + gc,
                  &Bs[(wave * 32 + i * 8) * 64 + lane * 8]);
        }
        __syncthreads();

        // --- two K=32 sub-steps: 8 frag reads + 16 MFMA each ---
        #pragma unroll
        for (int kk = 0; kk < 2; ++kk) {
            bf16x8_t af[4], bfr[4];
            #pragma unroll
            for (int i = 0; i < 4; i++) {
                const int r = wm + i * 16 + l15;
                af[i] = ld_bf8(&As[r * 64 + (((kk * 4 + quad) ^ (r & 7)) * 8)]);
            }
            #pragma unroll
            for (int j = 0; j < 4; j++) {
                const int r = wn + j * 16 + l15;
                bfr[j] = ld_bf8(&Bs[r * 64 + (((kk * 4 + quad) ^ (r & 7)) * 8)]);
            }
            #pragma unroll
            for (int i = 0; i < 4; i++)
                #pragma unroll
                for (int j = 0; j < 4; j++)
                    acc[i][j] = mfma16(af[i], bfr[j], acc[i][j]);
        }
        __syncthreads();
    }

    #pragma unroll
    for (int i = 0; i < 4; i++) {
        const int m = m0 + wm + i * 16 + quad * 4;
        #pragma unroll
        for (int j = 0; j < 4; j++) {
            const int gn = n0 + wn + j * 16 + l15;
            const float bb = bias[gn];
            const int h = gn >> 6, dh = gn & 63;
            if (z < 2) {
                u16* Y = z ? Kh : Qh;
                const int jc = dh >> 3, e = dh & 7;
                #pragma unroll
                for (int r = 0; r < 4; r++) {
                    const int mm = m + r;
                    const int b = mm >> 11, s = mm & 2047;
                    Y[((size_t)(b * 16 + h) * 2048 + s) * 64 + ((jc ^ (s & 7)) * 8) + e] =
                        f2bf(acc[i][j][r] + bb);
                }
            } else {
                const int b = m >> 11, sh = m & 2047, kt2 = sh >> 7, sl = sh & 127;
                const int poslow = ((sl >> 4) & 1) * 4;
                const int chunk = (sl >> 5) * 4 + ((sl >> 2) & 3);
                us4_t w4;
                #pragma unroll
                for (int r = 0; r < 4; r++) w4[r] = f2bf(acc[i][j][r] + bb);
                size_t off = (((size_t)(b * 16 + h) * 16 + kt2) * 8192)
                           + (size_t)dh * 128 + ((chunk ^ (dh & 7)) * 8) + poslow;
                *(us4_t*)&Vtt[off] = w4;
            }
        }
    }
}

// ---------------- output projection GEMM: 64x128 tile (exact R0-R2 version) ----------------
__global__ __launch_bounds__(256) void out_gemm_kernel(
    const u16* __restrict__ X, const u16* __restrict__ Wt,
    const float* __restrict__ bias, float* __restrict__ Y)
{
    __shared__ __align__(16) u16 As[2048];
    __shared__ __align__(16) u16 Bs[4096];
    const int m0 = blockIdx.x * 64, n0 = blockIdx.y * 128;
    const int tid = threadIdx.x, lane = tid & 63, wave = tid >> 6;
    const int l15 = lane & 15, quad = lane >> 4;
    const int wm = (wave & 1) * 32, wn = (wave >> 1) * 64;
    const int srow = lane >> 2, scol = (lane & 3) * 8;

    const f32x4_t z4 = {0.f, 0.f, 0.f, 0.f};
    f32x4_t acc[2][4];
    for (int i = 0; i < 2; i++) for (int j = 0; j < 4; j++) acc[i][j] = z4;

    for (int k0 = 0; k0 < 1024; k0 += 32) {
        dma16(X + (size_t)(m0 + wave * 16 + srow) * 1024 + k0 + scol,
              &As[wave * 512 + lane * 8]);
        #pragma unroll
        for (int i = 0; i < 2; i++)
            dma16(Wt + (size_t)(n0 + wave * 32 + i * 16 + srow) * 1024 + k0 + scol,
                  &Bs[wave * 1024 + i * 512 + lane * 8]);
        __syncthreads();
        bf16x8_t af[2], bfr[4];
        #pragma unroll
        for (int i = 0; i < 2; i++) af[i] = ld_bf8(&As[(wm + i * 16 + l15) * 32 + quad * 8]);
        #pragma unroll
        for (int j = 0; j < 4; j++) bfr[j] = ld_bf8(&Bs[(wn + j * 16 + l15) * 32 + quad * 8]);
        #pragma unroll
        for (int i = 0; i < 2; i++)
            #pragma unroll
            for (int j = 0; j < 4; j++)
                acc[i][j] = mfma16(af[i], bfr[j], acc[i][j]);
        __syncthreads();
    }

    #pragma unroll
    for (int i = 0; i < 2; i++) {
        const int m = m0 + wm + i * 16 + quad * 4;
        #pragma unroll
        for (int j = 0; j < 4; j++) {
            const int gn = n0 + wn + j * 16 + l15;
            const float bb = bias[gn];
            #pragma unroll
            for (int r = 0; r < 4; r++)
                Y[(size_t)(m + r) * 1024 + gn] = acc[i][j][r] + bb;
        }
    }
}

// ---------------- flash attention v7 (exact R2/R5 version, 62.6 us proven) ----------------
// KVBLK=64, psum via ones-MFMA, setprio. grid (h=16, qb=32, b=2). LDS 32KB.
__global__ __launch_bounds__(256, 4) void attn_kernel(
    const u16* __restrict__ Qh, const u16* __restrict__ Kh,
    const u16* __restrict__ Vtt, const unsigned* __restrict__ mp,
    u16* __restrict__ C)
{
    __shared__ __align__(16) u16 Ks[2][4096];
    __shared__ __align__(16) u16 Vs[2][4096];
    const int h = blockIdx.x, qb = blockIdx.y, b = blockIdx.z;
    const int tid = threadIdx.x, lane = tid & 63, wave = tid >> 6;
    const int l15 = lane & 15, quad = lane >> 4;
    const int q0 = qb * 64 + wave * 16;
    const int grow = b * 2048 + q0;
    const size_t headoff = (size_t)(b * 16 + h) * 131072;
    const u16* Qg = Qh + headoff;
    const u16* Kg = Kh + headoff;
    const u16* Vg = Vtt + headoff;

    bf16x8_t aq[2];
    #pragma unroll
    for (int ks = 0; ks < 2; ks++)
        aq[ks] = ld_bf8(Qg + (size_t)(q0 + l15) * 64 + (((ks * 4 + quad) ^ (l15 & 7)) * 8));

    us8_t ones_u;
    #pragma unroll
    for (int i = 0; i < 8; i++) ones_u[i] = 0x3F80;
    const bf16x8_t ones = __builtin_bit_cast(bf16x8_t, ones_u);

    const f32x4_t z4 = {0.f, 0.f, 0.f, 0.f};
    f32x4_t o[4];
    #pragma unroll
    for (int i = 0; i < 4; i++) o[i] = z4;
    f32x4_t osum = z4;

    const int swA = (quad ^ (l15 & 7)) * 8;
    const int swB = ((4 + quad) ^ (l15 & 7)) * 8;

    const unsigned* mrow = mp + (size_t)(b * 2048 + q0 + l15) * 64;

    auto stage = [&](int kt, int bs) {
        const u16* kg = Kg + kt * 4096 + wave * 1024;
        const u16* vg = Vg + (kt >> 1) * 8192 + (kt & 1) * 64;
        u16* kl = &Ks[bs][wave * 1024];
        u16* vl = &Vs[bs][wave * 1024];
        #pragma unroll
        for (int i = 0; i < 2; i++) {
            dma16(kg + i * 512 + lane * 8, kl + i * 512 + lane * 8);
            dma16(vg + (size_t)(wave * 16 + i * 8 + (lane >> 3)) * 128 + (lane & 7) * 8,
                  vl + i * 512 + lane * 8);
        }
    };

    stage(0, 0);

    for (int kt = 0; kt < 32; ++kt) {
        const int bs = kt & 1;
        __syncthreads();
        if (kt < 31) stage(kt + 1, bs ^ 1);

        const int2 mv = *(const int2*)(mrow + kt * 2);

        f32x4_t sc[4];
        __builtin_amdgcn_s_setprio(1);
        #pragma unroll
        for (int st = 0; st < 4; st++) {
            const u16* kp = &Ks[bs][(st * 16 + l15) * 64];
            bf16x8_t k0 = ld_bf8(kp + swA);
            bf16x8_t k1 = ld_bf8(kp + swB);
            sc[st] = mfma16(k1, aq[1], mfma16(k0, aq[0], z4));
        }
        __builtin_amdgcn_s_setprio(0);

        us8_t ap[2];
        #pragma unroll
        for (int st = 0; st < 4; st++) {
            const unsigned w = (st < 2) ? (unsigned)mv.x : (unsigned)mv.y;
            const int shbase = ((st & 1) << 4) + quad * 4;
            #pragma unroll
            for (int r = 0; r < 4; r++) {
                const bool msk = (w >> (shbase + r)) & 1u;
                const float t = fmaf(sc[st][r], 0.18033688011f, msk ? -1e5f : -17.312340491f);
                ap[st >> 1][((st & 1) << 2) + r] = f2bf(exp2_fast(t));
            }
        }

        __builtin_amdgcn_s_setprio(1);
        #pragma unroll
        for (int c = 0; c < 2; c++) {
            bf16x8_t a = __builtin_bit_cast(bf16x8_t, ap[c]);
            osum = mfma16(a, ones, osum);
            #pragma unroll
            for (int nt = 0; nt < 4; nt++) {
                bf16x8_t bv = ld_bf8(&Vs[bs][(nt * 16 + l15) * 64
                                             + (((c * 4 + quad) ^ (l15 & 7)) * 8)]);
                o[nt] = mfma16(a, bv, o[nt]);
            }
        }
        __builtin_amdgcn_s_setprio(0);
    }

    #pragma unroll
    for (int r = 0; r < 4; r++) {
        const float invl = 1.0f / osum[r];
        const int row = grow + quad * 4 + r;
        #pragma unroll
        for (int nt = 0; nt < 4; nt++)
            C[(size_t)row * 1024 + h * 64 + nt * 16 + l15] = f2bf(o[nt][r] * invl);
    }
}

extern "C" void kernel_launch(void* const* d_in, const int* in_sizes, int n_in,
                              void* d_out, int out_size, void* d_ws, size_t ws_size,
                              hipStream_t stream) {
    const float* q    = (const float*)d_in[0];
    const float* k    = (const float*)d_in[1];
    const float* v    = (const float*)d_in[2];
    const int*   mask = (const int*)d_in[3];
    const float* wq   = (const float*)d_in[4];
    const float* bq   = (const float*)d_in[5];
    const float* wk   = (const float*)d_in[6];
    const float* bk   = (const float*)d_in[7];
    const float* wv   = (const float*)d_in[8];
    const float* bv   = (const float*)d_in[9];
    const float* wo   = (const float*)d_in[10];
    const float* bo   = (const float*)d_in[11];
    float* out = (float*)d_out;

    char* ws = (char*)d_ws;
    const size_t MB = 1ull << 20;
    u16* Wt      = (u16*)(ws);              // 8 MB: 4 weights bf16 [n][k]
    u16* Qc      = (u16*)(ws + 8 * MB);     // 8 MB bf16 input q
    u16* Kc      = (u16*)(ws + 16 * MB);    // 8 MB bf16 input k
    u16* Vc      = (u16*)(ws + 24 * MB);    // 8 MB bf16 input v
    u16* Qhh     = (u16*)(ws + 32 * MB);    // 8 MB head-major swizzled
    u16* Khh     = (u16*)(ws + 40 * MB);    // 8 MB head-major swizzled
    u16* Vtt     = (u16*)(ws + 48 * MB);    // 8 MB tiled sigma-permuted swizzled
    u16* CT      = (u16*)(ws + 8 * MB);     // reuse Qc (dead after qkv_gemm)
    unsigned* mp = (unsigned*)(ws + 56 * MB); // 1 MB

    prep_kernel<<<dim3(8192), 256, 0, stream>>>(
        q, k, v, mask, wq, wk, wv, wo, Qc, Kc, Vc, Wt, mp);

    qkv_gemm_kernel<<<dim3(32, 8, 3), 256, 0, stream>>>(
        Qc, Kc, Vc, Wt, bq, bk, bv, Qhh, Khh, Vtt);

    attn_kernel<<<dim3(16, 32, 2), 256, 0, stream>>>(Qhh, Khh, Vtt, mp, CT);

    out_gemm_kernel<<<dim3(64, 8), 256, 0, stream>>>(CT, Wt + 3ull * 1048576, bo, out);
}

// Round 10
// 257.731 us; speedup vs baseline: 1.2889x; 1.0128x over previous
//
#include <hip/hip_runtime.h>

typedef unsigned short u16;
typedef __bf16 bf16x8_t __attribute__((ext_vector_type(8)));
typedef float  f32x4_t  __attribute__((ext_vector_type(4)));
typedef u16    us8_t    __attribute__((ext_vector_type(8)));
typedef u16    us4_t    __attribute__((ext_vector_type(4)));

__device__ __forceinline__ u16 f2bf(float f) {
    __bf16 h = (__bf16)f;
    return __builtin_bit_cast(u16, h);
}
__device__ __forceinline__ bf16x8_t ld_bf8(const u16* p) {
    us8_t u = *(const us8_t*)p;
    return __builtin_bit_cast(bf16x8_t, u);
}
__device__ __forceinline__ f32x4_t mfma16(bf16x8_t a, bf16x8_t b, f32x4_t c) {
    return __builtin_amdgcn_mfma_f32_16x16x32_bf16(a, b, c, 0, 0, 0);
}
__device__ __forceinline__ float exp2_fast(float x) {
#if __has_builtin(__builtin_amdgcn_exp2f)
    return __builtin_amdgcn_exp2f(x);
#else
    return exp2f(x);
#endif
}

// async global->LDS, 16B per lane. LDS dest MUST be base + lane*16 (wave-uniform base).
__device__ __forceinline__ void dma16(const u16* g, u16* l) {
#if __has_builtin(__builtin_amdgcn_global_load_lds)
    __builtin_amdgcn_global_load_lds((const __attribute__((address_space(1))) unsigned int*)(g),
                                     (__attribute__((address_space(3))) unsigned int*)(l), 16, 0, 0);
#else
    *(us8_t*)l = *(const us8_t*)g;
#endif
}

// ---------------- fused prep: cvt (6144 blk) + weight transpose (1024) + mask pack (1024) ----
// (exact R2 version — part of the best-measured 256.3 us config)
__global__ __launch_bounds__(256) void prep_kernel(
    const float* __restrict__ q, const float* __restrict__ k, const float* __restrict__ v,
    const int* __restrict__ mask,
    const float* __restrict__ w0, const float* __restrict__ w1,
    const float* __restrict__ w2, const float* __restrict__ w3,
    u16* __restrict__ Qc, u16* __restrict__ Kc, u16* __restrict__ Vc,
    u16* __restrict__ Wt, unsigned* __restrict__ mp)
{
    __shared__ u16 t[64][65];
    const int bid = blockIdx.x, tid = threadIdx.x;
    if (bid < 6144) {
        // fp32 -> bf16 convert of q,k,v
        const int z = bid >> 11, x = bid & 2047;
        const float* src = (z == 0) ? q : (z == 1) ? k : v;
        u16* dst = (z == 0) ? Qc : (z == 1) ? Kc : Vc;
        const size_t i = ((size_t)x * 256 + tid) * 8;
        float4 a = *(const float4*)(src + i);
        float4 b = *(const float4*)(src + i + 4);
        us8_t w;
        w[0] = f2bf(a.x); w[1] = f2bf(a.y); w[2] = f2bf(a.z); w[3] = f2bf(a.w);
        w[4] = f2bf(b.x); w[5] = f2bf(b.y); w[6] = f2bf(b.z); w[7] = f2bf(b.w);
        *(us8_t*)(dst + i) = w;
    } else if (bid < 7168) {
        // weight transpose+convert: fp32 [k][n] -> bf16 [n][k]
        const int r2 = bid - 6144;
        const int z = r2 >> 8, rem = r2 & 255;
        const float* src = (z == 0) ? w0 : (z == 1) ? w1 : (z == 2) ? w2 : w3;
        u16* dst = Wt + (size_t)z * 1048576;
        const int bk = (rem & 15) * 64, bn = (rem >> 4) * 64;
        const int r = tid >> 2, c4 = tid & 3;
        for (int i = 0; i < 4; i++) {
            float4 vv = *(const float4*)(src + (size_t)(bk + r) * 1024 + bn + c4 * 16 + i * 4);
            t[r][c4 * 16 + i * 4 + 0] = f2bf(vv.x);
            t[r][c4 * 16 + i * 4 + 1] = f2bf(vv.y);
            t[r][c4 * 16 + i * 4 + 2] = f2bf(vv.z);
            t[r][c4 * 16 + i * 4 + 3] = f2bf(vv.w);
        }
        __syncthreads();
        for (int i = 0; i < 2; i++) {
            us8_t w;
            for (int j = 0; j < 8; j++) w[j] = t[c4 * 16 + i * 8 + j][r];
            *(us8_t*)(dst + (size_t)(bn + r) * 1024 + bk + c4 * 16 + i * 8) = w;
        }
    } else {
        // mask pack: 1 bit per key
        const int w = (bid - 7168) * 256 + tid;
        const int* src = mask + (size_t)w * 32;
        unsigned bits = 0u;
        for (int i = 0; i < 32; i += 4) {
            int4 vv = *(const int4*)(src + i);
            bits |= (unsigned)(vv.x != 0) << (i + 0);
            bits |= (unsigned)(vv.y != 0) << (i + 1);
            bits |= (unsigned)(vv.z != 0) << (i + 2);
            bits |= (unsigned)(vv.w != 0) << (i + 3);
        }
        mp[w] = bits;
    }
}

// ---------------- fused QKV projection GEMM (exact R2 version: m97-style, DMA staging) ------
__global__ __launch_bounds__(256) void qkv_gemm_kernel(
    const u16* __restrict__ Qc, const u16* __restrict__ Kc, const u16* __restrict__ Vc,
    const u16* __restrict__ Wt,
    const float* __restrict__ bq, const float* __restrict__ bk, const float* __restrict__ bv,
    u16* __restrict__ Qh, u16* __restrict__ Kh, u16* __restrict__ Vtt)
{
    __shared__ __align__(16) u16 As[4096];
    __shared__ __align__(16) u16 Bs[4096];
    const int z = blockIdx.z;
    const u16* A = (z == 0) ? Qc : (z == 1) ? Kc : Vc;
    const u16* W = Wt + (size_t)z * 1048576;
    const float* bias = (z == 0) ? bq : (z == 1) ? bk : bv;

    const int m0 = blockIdx.x * 128, n0 = blockIdx.y * 128;
    const int tid = threadIdx.x, lane = tid & 63, wave = tid >> 6;
    const int l15 = lane & 15, quad = lane >> 4;
    const int wm = (wave & 1) * 64, wn = (wave >> 1) * 64;
    const int srow = lane >> 2, scol = (lane & 3) * 8;

    const f32x4_t z4 = {0.f, 0.f, 0.f, 0.f};
    f32x4_t acc[4][4];
    for (int i = 0; i < 4; i++) for (int j = 0; j < 4; j++) acc[i][j] = z4;

    for (int k0 = 0; k0 < 1024; k0 += 32) {
        #pragma unroll
        for (int i = 0; i < 2; i++) {
            dma16(A + (size_t)(m0 + wave * 32 + i * 16 + srow) * 1024 + k0 + scol,
                  &As[wave * 1024 + i * 512 + lane * 8]);
            dma16(W + (size_t)(n0 + wave * 32 + i * 16 + srow) * 1024 + k0 + scol,
                  &Bs[wave * 1024 + i * 512 + lane * 8]);
        }
        __syncthreads();
        bf16x8_t af[4], bfr[4];
        #pragma unroll
        for (int i = 0; i < 4; i++) af[i] = ld_bf8(&As[(wm + i * 16 + l15) * 32 + quad * 8]);
        #pragma unroll
        for (int j = 0; j < 4; j++) bfr[j] = ld_bf8(&Bs[(wn + j * 16 + l15) * 32 + quad * 8]);
        #pragma unroll
        for (int i = 0; i < 4; i++)
            #pragma unroll
            for (int j = 0; j < 4; j++)
                acc[i][j] = mfma16(af[i], bfr[j], acc[i][j]);
        __syncthreads();
    }

    #pragma unroll
    for (int i = 0; i < 4; i++) {
        const int m = m0 + wm + i * 16 + quad * 4;
        #pragma unroll
        for (int j = 0; j < 4; j++) {
            const int gn = n0 + wn + j * 16 + l15;
            const float bb = bias[gn];
            const int h = gn >> 6, dh = gn & 63;
            if (z < 2) {
                u16* Y = z ? Kh : Qh;
                const int jc = dh >> 3, e = dh & 7;
                #pragma unroll
                for (int r = 0; r < 4; r++) {
                    const int mm = m + r;
                    const int b = mm >> 11, s = mm & 2047;
                    Y[((size_t)(b * 16 + h) * 2048 + s) * 64 + ((jc ^ (s & 7)) * 8) + e] =
                        f2bf(acc[i][j][r] + bb);
                }
            } else {
                const int b = m >> 11, sh = m & 2047, kt2 = sh >> 7, sl = sh & 127;
                const int poslow = ((sl >> 4) & 1) * 4;
                const int chunk = (sl >> 5) * 4 + ((sl >> 2) & 3);
                us4_t w4;
                #pragma unroll
                for (int r = 0; r < 4; r++) w4[r] = f2bf(acc[i][j][r] + bb);
                size_t off = (((size_t)(b * 16 + h) * 16 + kt2) * 8192)
                           + (size_t)dh * 128 + ((chunk ^ (dh & 7)) * 8) + poslow;
                *(us4_t*)&Vtt[off] = w4;
            }
        }
    }
}

// ---------------- output projection GEMM: 64x128 tile (exact R2 version) ----------------
__global__ __launch_bounds__(256) void out_gemm_kernel(
    const u16* __restrict__ X, const u16* __restrict__ Wt,
    const float* __restrict__ bias, float* __restrict__ Y)
{
    __shared__ __align__(16) u16 As[2048];
    __shared__ __align__(16) u16 Bs[4096];
    const int m0 = blockIdx.x * 64, n0 = blockIdx.y * 128;
    const int tid = threadIdx.x, lane = tid & 63, wave = tid >> 6;
    const int l15 = lane & 15, quad = lane >> 4;
    const int wm = (wave & 1) * 32, wn = (wave >> 1) * 64;
    const int srow = lane >> 2, scol = (lane & 3) * 8;

    const f32x4_t z4 = {0.f, 0.f, 0.f, 0.f};
    f32x4_t acc[2][4];
    for (int i = 0; i < 2; i++) for (int j = 0; j < 4; j++) acc[i][j] = z4;

    for (int k0 = 0; k0 < 1024; k0 += 32) {
        dma16(X + (size_t)(m0 + wave * 16 + srow) * 1024 + k0 + scol,
              &As[wave * 512 + lane * 8]);
        #pragma unroll
        for (int i = 0; i < 2; i++)
            dma16(Wt + (size_t)(n0 + wave * 32 + i * 16 + srow) * 1024 + k0 + scol,
                  &Bs[wave * 1024 + i * 512 + lane * 8]);
        __syncthreads();
        bf16x8_t af[2], bfr[4];
        #pragma unroll
        for (int i = 0; i < 2; i++) af[i] = ld_bf8(&As[(wm + i * 16 + l15) * 32 + quad * 8]);
        #pragma unroll
        for (int j = 0; j < 4; j++) bfr[j] = ld_bf8(&Bs[(wn + j * 16 + l15) * 32 + quad * 8]);
        #pragma unroll
        for (int i = 0; i < 2; i++)
            #pragma unroll
            for (int j = 0; j < 4; j++)
                acc[i][j] = mfma16(af[i], bfr[j], acc[i][j]);
        __syncthreads();
    }

    #pragma unroll
    for (int i = 0; i < 2; i++) {
        const int m = m0 + wm + i * 16 + quad * 4;
        #pragma unroll
        for (int j = 0; j < 4; j++) {
            const int gn = n0 + wn + j * 16 + l15;
            const float bb = bias[gn];
            #pragma unroll
            for (int r = 0; r < 4; r++)
                Y[(size_t)(m + r) * 1024 + gn] = acc[i][j][r] + bb;
        }
    }
}

// ---------------- flash attention v9: v7 + PV ROTATION (deferred one iteration) ----------
// Iter kt: [PV(kt-1) from Vs[bs^1]] -> barrier -> stage(kt+1)->buf bs^1 -> QK(kt) ->
// softmax(kt)->ap. Buffer safety: PV(kt-1)'s ds_reads complete before the barrier
// (__syncthreads drains lgkmcnt); stage(kt+1) overwrites Vs[bs^1] only after it.
// Mechanism (T15): PV's 10 MFMA now fill the barrier-arrival skew window, and the
// softmax->PV dependency spans the backedge instead of stalling in-iter.
// Everything else identical to v7 (62.6 us proven): KVBLK=64, psum via ones-MFMA,
// setprio, fixed-max exp2 softmax, sigma-permuted V.
__global__ __launch_bounds__(256, 4) void attn_kernel(
    const u16* __restrict__ Qh, const u16* __restrict__ Kh,
    const u16* __restrict__ Vtt, const unsigned* __restrict__ mp,
    u16* __restrict__ C)
{
    __shared__ __align__(16) u16 Ks[2][4096];
    __shared__ __align__(16) u16 Vs[2][4096];
    const int h = blockIdx.x, qb = blockIdx.y, b = blockIdx.z;
    const int tid = threadIdx.x, lane = tid & 63, wave = tid >> 6;
    const int l15 = lane & 15, quad = lane >> 4;
    const int q0 = qb * 64 + wave * 16;
    const int grow = b * 2048 + q0;
    const size_t headoff = (size_t)(b * 16 + h) * 131072;
    const u16* Qg = Qh + headoff;
    const u16* Kg = Kh + headoff;
    const u16* Vg = Vtt + headoff;

    bf16x8_t aq[2];
    #pragma unroll
    for (int ks = 0; ks < 2; ks++)
        aq[ks] = ld_bf8(Qg + (size_t)(q0 + l15) * 64 + (((ks * 4 + quad) ^ (l15 & 7)) * 8));

    us8_t ones_u;
    #pragma unroll
    for (int i = 0; i < 8; i++) ones_u[i] = 0x3F80;
    const bf16x8_t ones = __builtin_bit_cast(bf16x8_t, ones_u);

    const f32x4_t z4 = {0.f, 0.f, 0.f, 0.f};
    f32x4_t o[4];
    #pragma unroll
    for (int i = 0; i < 4; i++) o[i] = z4;
    f32x4_t osum = z4;

    const int swA = (quad ^ (l15 & 7)) * 8;
    const int swB = ((4 + quad) ^ (l15 & 7)) * 8;

    const unsigned* mrow = mp + (size_t)(b * 2048 + q0 + l15) * 64;

    auto stage = [&](int kt, int bs) {
        const u16* kg = Kg + kt * 4096 + wave * 1024;
        const u16* vg = Vg + (kt >> 1) * 8192 + (kt & 1) * 64;
        u16* kl = &Ks[bs][wave * 1024];
        u16* vl = &Vs[bs][wave * 1024];
        #pragma unroll
        for (int i = 0; i < 2; i++) {
            dma16(kg + i * 512 + lane * 8, kl + i * 512 + lane * 8);
            dma16(vg + (size_t)(wave * 16 + i * 8 + (lane >> 3)) * 128 + (lane & 7) * 8,
                  vl + i * 512 + lane * 8);
        }
    };

    // PV for tile (from buffer vb) using A-fragments ap
    us8_t ap[2];
    auto pv = [&](int vb) {
        __builtin_amdgcn_s_setprio(1);
        #pragma unroll
        for (int c = 0; c < 2; c++) {
            bf16x8_t a = __builtin_bit_cast(bf16x8_t, ap[c]);
            osum = mfma16(a, ones, osum);
            #pragma unroll
            for (int nt = 0; nt < 4; nt++) {
                bf16x8_t bv = ld_bf8(&Vs[vb][(nt * 16 + l15) * 64
                                             + (((c * 4 + quad) ^ (l15 & 7)) * 8)]);
                o[nt] = mfma16(a, bv, o[nt]);
            }
        }
        __builtin_amdgcn_s_setprio(0);
    };

    stage(0, 0);

    for (int kt = 0; kt < 32; ++kt) {
        const int bs = kt & 1;

        if (kt > 0) pv(bs ^ 1);       // PV(kt-1): V in buf (kt-1)&1, before the barrier

        __syncthreads();              // drains stage(kt) into bs; PV reads are complete
        if (kt < 31) stage(kt + 1, bs ^ 1);

        const int2 mv = *(const int2*)(mrow + kt * 2);

        // --- S^T = K.Q^T : rows=keys (64), cols=qrows (16) ---
        f32x4_t sc[4];
        __builtin_amdgcn_s_setprio(1);
        #pragma unroll
        for (int st = 0; st < 4; st++) {
            const u16* kp = &Ks[bs][(st * 16 + l15) * 64];
            bf16x8_t k0 = ld_bf8(kp + swA);
            bf16x8_t k1 = ld_bf8(kp + swB);
            sc[st] = mfma16(k1, aq[1], mfma16(k0, aq[0], z4));
        }
        __builtin_amdgcn_s_setprio(0);

        // --- fixed-max softmax in registers (exp2, log2e pre-folded) -> ap for next iter ---
        #pragma unroll
        for (int st = 0; st < 4; st++) {
            const unsigned w = (st < 2) ? (unsigned)mv.x : (unsigned)mv.y;
            const int shbase = ((st & 1) << 4) + quad * 4;
            #pragma unroll
            for (int r = 0; r < 4; r++) {
                const bool msk = (w >> (shbase + r)) & 1u;
                const float t = fmaf(sc[st][r], 0.18033688011f, msk ? -1e5f : -17.312340491f);
                ap[st >> 1][((st & 1) << 2) + r] = f2bf(exp2_fast(t));
            }
        }
    }

    pv(1);                            // PV(31): V in buf 31&1 = 1

    #pragma unroll
    for (int r = 0; r < 4; r++) {
        const float invl = 1.0f / osum[r];
        const int row = grow + quad * 4 + r;
        #pragma unroll
        for (int nt = 0; nt < 4; nt++)
            C[(size_t)row * 1024 + h * 64 + nt * 16 + l15] = f2bf(o[nt][r] * invl);
    }
}

extern "C" void kernel_launch(void* const* d_in, const int* in_sizes, int n_in,
                              void* d_out, int out_size, void* d_ws, size_t ws_size,
                              hipStream_t stream) {
    const float* q    = (const float*)d_in[0];
    const float* k    = (const float*)d_in[1];
    const float* v    = (const float*)d_in[2];
    const int*   mask = (const int*)d_in[3];
    const float* wq   = (const float*)d_in[4];
    const float* bq   = (const float*)d_in[5];
    const float* wk   = (const float*)d_in[6];
    const float* bk   = (const float*)d_in[7];
    const float* wv   = (const float*)d_in[8];
    const float* bv   = (const float*)d_in[9];
    const float* wo   = (const float*)d_in[10];
    const float* bo   = (const float*)d_in[11];
    float* out = (float*)d_out;

    char* ws = (char*)d_ws;
    const size_t MB = 1ull << 20;
    u16* Wt      = (u16*)(ws);              // 8 MB: 4 weights bf16 [n][k]
    u16* Qc      = (u16*)(ws + 8 * MB);     // 8 MB bf16 input q
    u16* Kc      = (u16*)(ws + 16 * MB);    // 8 MB bf16 input k
    u16* Vc      = (u16*)(ws + 24 * MB);    // 8 MB bf16 input v
    u16* Qhh     = (u16*)(ws + 32 * MB);    // 8 MB head-major swizzled
    u16* Khh     = (u16*)(ws + 40 * MB);    // 8 MB head-major swizzled
    u16* Vtt     = (u16*)(ws + 48 * MB);    // 8 MB tiled sigma-permuted swizzled
    u16* CT      = (u16*)(ws + 8 * MB);     // reuse Qc (dead after qkv_gemm)
    unsigned* mp = (unsigned*)(ws + 56 * MB); // 1 MB

    prep_kernel<<<dim3(8192), 256, 0, stream>>>(
        q, k, v, mask, wq, wk, wv, wo, Qc, Kc, Vc, Wt, mp);

    qkv_gemm_kernel<<<dim3(32, 8, 3), 256, 0, stream>>>(
        Qc, Kc, Vc, Wt, bq, bk, bv, Qhh, Khh, Vtt);

    attn_kernel<<<dim3(16, 32, 2), 256, 0, stream>>>(Qhh, Khh, Vtt, mp, CT);

    out_gemm_kernel<<<dim3(64, 8), 256, 0, stream>>>(CT, Wt + 3ull * 1048576, bo, out);
}